// Round 3
// baseline (8020.692 us; speedup 1.0000x reference)
//
#include <hip/hip_runtime.h>
#include <math.h>

// Deep ESN, fp32, persistent wavefront-pipelined kernel, round 10.
// R9 (1024 thr, 4-way k-split, __launch_bounds__(1024,4)) hit a register
// trap: the waves-per-EU hint capped the allocator at 64 VGPRs, but the
// accumulator alone needs 64 -> massive scratch spills (hbm_bytes 1.7GB ->
// 13.8GB, WRITE_SIZE 15x). R10: identical structure, launch bounds relaxed
// to __launch_bounds__(1024) -- the 1024-thread workgroup itself caps VGPR
// at 128 (4 waves/SIMD), which R8 proved is enough for this inner loop.

#define TT    512
#define RDIM  1024
#define EDIM  256
#define NL    4
#define BB    32
#define NBLK  256          // 64 blocks per layer
#define JW    16           // output columns per block
#define HDIM  (RDIM * NL)  // 4096
#define NPAN  4            // 4 panels of 8 batch rows
#define NKH   4            // k-split ways
#define CSTRIDE 32         // dwords between counter words (128B lines)

#define S_ELEMS   (2 * NL * NPAN * RDIM * 8)   // 2 parities, 1MB
#define FIN_ELEMS (BB * HDIM)

typedef float vf2 __attribute__((ext_vector_type(2)));
typedef unsigned long long ull;

__device__ __forceinline__ float2 aload2(const ull* p) {   // 8B sc1 load
    ull u = __hip_atomic_load(p, __ATOMIC_RELAXED, __HIP_MEMORY_SCOPE_AGENT);
    union { ull u; float2 f; } c; c.u = u; return c.f;
}
__device__ __forceinline__ float dpp_xor1(float x) {   // lane ^ 1
    return __int_as_float(__builtin_amdgcn_mov_dpp(__float_as_int(x), 0xB1, 0xF, 0xF, true));
}
__device__ __forceinline__ float dpp_xor2(float x) {   // lane ^ 2
    return __int_as_float(__builtin_amdgcn_mov_dpp(__float_as_int(x), 0x4E, 0xF, 0xF, true));
}

// ---------------------------------------------------------------- gather ----
// xe[t][panel][k][8b] : panel layout matching reservoir reads
__global__ void gather_kernel(const int* __restrict__ x,
                              const float* __restrict__ embed,
                              float* __restrict__ xe)
{
    __shared__ int   ids[BB];
    __shared__ float sh[BB * (EDIM + 1)];
    const int t = blockIdx.x, tid = threadIdx.x;
    if (tid < BB) ids[tid] = x[tid * TT + t];
    __syncthreads();
    for (int r = 0; r < BB; ++r)
        sh[r * (EDIM + 1) + tid] = embed[ids[r] * EDIM + tid];
    __syncthreads();
    for (int i = tid; i < NPAN * EDIM * 8; i += 256) {
        int p = i >> 11, k = (i >> 3) & (EDIM - 1), bo = i & 7;
        xe[(size_t)t * (NPAN * EDIM * 8) + i] = sh[(p * 8 + bo) * (EDIM + 1) + k];
    }
}

// ------------------------------------------------------------- reservoir ----
__global__ __launch_bounds__(1024) void reservoir_kernel(
    const float* __restrict__ Win0, const float* __restrict__ WinR,
    const float* __restrict__ Rst,  const float* __restrict__ xe,
    float* __restrict__ S, float* __restrict__ Fin,
    unsigned* __restrict__ cnt, unsigned* __restrict__ rel)
{
    __shared__ float Wlds[2048 * JW];                  // 128 KB, row k = 16 floats
    __shared__ float Pbuf[(NKH - 1) * NPAN * JW * 8];  // 6 KB, cross-wave partials
    const int tid   = threadIdx.x;
    const int blk   = blockIdx.x;
    const int layer = blk >> 6;
    const int j0    = (blk & 63) * JW;
    const int Kin   = (layer == 0) ? EDIM : RDIM;

    // rows [0,1024) = R_stack col-slice, rows [1024,1024+Kin) = Win col-slice
    for (int idx = tid; idx < (RDIM + Kin) * JW; idx += 1024) {
        int k = idx >> 4, j = idx & 15;
        float wv;
        if (k < RDIM) wv = Rst[((size_t)layer * RDIM + k) * RDIM + j0 + j];
        else {
            int k2 = k - RDIM;
            wv = (layer == 0) ? Win0[(size_t)k2 * RDIM + j0 + j]
                              : WinR[((size_t)(layer - 1) * RDIM + k2) * RDIM + j0 + j];
        }
        Wlds[idx] = wv;
    }
    __syncthreads();

    const int w16 = tid >> 6;   // 16 waves
    const int w   = w16 & 3;    // panel (8 batch rows)
    const int kh  = w16 >> 2;   // k-quarter: wave reads a disjoint k-slice
    const int lam = tid & 63;
    const int kq  = lam >> 1;   // 32-way k split within wave
    const int bh  = lam & 1;    // which float4 of the 8-wide batch row
    const int bh4 = bh * 4;

    for (int tick = 0; tick < TT + NL - 1; ++tick) {
        const int t = tick - layer;
        if (t >= 0 && t < TT) {
            const int cur = tick & 1, prv = (tick - 1) & 1;
            const ull* ownp = (const ull*)(S + (((size_t)(prv * NL + layer)) * NPAN + w) * RDIM * 8);
            const ull* inps = (const ull*)(S + (((size_t)(prv * NL + layer - 1)) * NPAN + w) * RDIM * 8);
            const float4* inpx = (const float4*)(xe + ((size_t)t * NPAN + w) * (EDIM * 8));

            vf2 acc[4][8];
            #pragma unroll
            for (int i = 0; i < 4; ++i)
                #pragma unroll
                for (int jp = 0; jp < 8; ++jp) acc[i][jp] = (vf2)(0.f);

            // ---- own state @ R_stack (sc1 loads), this wave's k-quarter ----
            #pragma unroll 8
            for (int kk2 = 0; kk2 < RDIM / (32 * NKH); ++kk2) {
                const int kk = kh * (RDIM / (32 * NKH)) + kk2;
                const ull* p = ownp + (size_t)kk * 128 + lam * 2;   // 1KB/wave
                float2 v0 = aload2(p), v1 = aload2(p + 1);
                const int k = kk * 32 + kq;
                float4 wo0 = *(const float4*)&Wlds[k * JW + bh * 8];
                float4 wo1 = *(const float4*)&Wlds[k * JW + bh * 8 + 4];
                vf2 wv[8];
                wv[0] = (vf2){wo0.x, wo0.y}; wv[1] = (vf2){wo0.z, wo0.w};
                wv[2] = (vf2){wo1.x, wo1.y}; wv[3] = (vf2){wo1.z, wo1.w};
                wv[4] = (vf2){dpp_xor1(wo0.x), dpp_xor1(wo0.y)};
                wv[5] = (vf2){dpp_xor1(wo0.z), dpp_xor1(wo0.w)};
                wv[6] = (vf2){dpp_xor1(wo1.x), dpp_xor1(wo1.y)};
                wv[7] = (vf2){dpp_xor1(wo1.z), dpp_xor1(wo1.w)};
                const float vv[4] = {v0.x, v0.y, v1.x, v1.y};
                #pragma unroll
                for (int i = 0; i < 4; ++i) {
                    vf2 s = {vv[i], vv[i]};
                    #pragma unroll
                    for (int jp = 0; jp < 8; ++jp) acc[i][jp] += s * wv[jp];
                }
            }
            // ---- layer input @ Win, this wave's k-quarter ----
            #pragma unroll 8
            for (int kk2 = 0; kk2 < Kin / (32 * NKH); ++kk2) {
                const int kk = kh * (Kin / (32 * NKH)) + kk2;
                float2 v0, v1;
                if (layer == 0) {                       // xe: read-only, cached
                    float4 v = inpx[(size_t)kk * 64 + lam];
                    v0 = (float2){v.x, v.y}; v1 = (float2){v.z, v.w};
                } else {                                // state: sc1
                    const ull* p = inps + (size_t)kk * 128 + lam * 2;
                    v0 = aload2(p); v1 = aload2(p + 1);
                }
                const int k = RDIM + kk * 32 + kq;
                float4 wo0 = *(const float4*)&Wlds[k * JW + bh * 8];
                float4 wo1 = *(const float4*)&Wlds[k * JW + bh * 8 + 4];
                vf2 wv[8];
                wv[0] = (vf2){wo0.x, wo0.y}; wv[1] = (vf2){wo0.z, wo0.w};
                wv[2] = (vf2){wo1.x, wo1.y}; wv[3] = (vf2){wo1.z, wo1.w};
                wv[4] = (vf2){dpp_xor1(wo0.x), dpp_xor1(wo0.y)};
                wv[5] = (vf2){dpp_xor1(wo0.z), dpp_xor1(wo0.w)};
                wv[6] = (vf2){dpp_xor1(wo1.x), dpp_xor1(wo1.y)};
                wv[7] = (vf2){dpp_xor1(wo1.z), dpp_xor1(wo1.w)};
                const float vv[4] = {v0.x, v0.y, v1.x, v1.y};
                #pragma unroll
                for (int i = 0; i < 4; ++i) {
                    vf2 s = {vv[i], vv[i]};
                    #pragma unroll
                    for (int jp = 0; jp < 8; ++jp) acc[i][jp] += s * wv[jp];
                }
            }

            // ---- reduce-scatter over kq: 64 accs -> 2 partials per lane ----
            float r64v[64];
            #pragma unroll
            for (int i = 0; i < 4; ++i)
                #pragma unroll
                for (int jp = 0; jp < 8; ++jp) {
                    r64v[(i << 4) | (jp << 1)]     = acc[i][jp].x;
                    r64v[(i << 4) | (jp << 1) | 1] = acc[i][jp].y;
                }
            float r32v[32], r16v[16], r8v[8], r4v[4], rfin[2];
            {   const bool myb = kq & 1;                 // stage 0: DPP xor2
                #pragma unroll
                for (int m = 0; m < 32; ++m) {
                    float a = r64v[2 * m], b = r64v[2 * m + 1];
                    float send = myb ? a : b, keep = myb ? b : a;
                    r32v[m] = keep + dpp_xor2(send);
                }
            }
            {   const bool myb = (kq >> 1) & 1;          // stage 1: xor 4
                #pragma unroll
                for (int m = 0; m < 16; ++m) {
                    float a = r32v[2 * m], b = r32v[2 * m + 1];
                    float send = myb ? a : b, keep = myb ? b : a;
                    r16v[m] = keep + __shfl_xor(send, 4, 64);
                }
            }
            {   const bool myb = (kq >> 2) & 1;          // stage 2: xor 8
                #pragma unroll
                for (int m = 0; m < 8; ++m) {
                    float a = r16v[2 * m], b = r16v[2 * m + 1];
                    float send = myb ? a : b, keep = myb ? b : a;
                    r8v[m] = keep + __shfl_xor(send, 8, 64);
                }
            }
            {   const bool myb = (kq >> 3) & 1;          // stage 3: xor 16
                #pragma unroll
                for (int m = 0; m < 4; ++m) {
                    float a = r8v[2 * m], b = r8v[2 * m + 1];
                    float send = myb ? a : b, keep = myb ? b : a;
                    r4v[m] = keep + __shfl_xor(send, 16, 64);
                }
            }
            {   const bool myb = (kq >> 4) & 1;          // stage 4: xor 32
                #pragma unroll
                for (int m = 0; m < 2; ++m) {
                    float a = r4v[2 * m], b = r4v[2 * m + 1];
                    float send = myb ? a : b, keep = myb ? b : a;
                    rfin[m] = keep + __shfl_xor(send, 32, 64);
                }
            }

            // ---- cross-wave k-quarter combine via LDS, then epilogue ----
            const int i0 = kq >> 4;                 // 0..1
            const int cc = kq & 15;
            const int j  = (cc & 7) + 8 * (bh ^ (cc >> 3));   // logical col
            if (kh) {                               // k-quarters 1..3: publish
                #pragma unroll
                for (int m = 0; m < 2; ++m)
                    Pbuf[(((kh - 1) * NPAN + w) * JW + j) * 8 + (bh4 + i0 + 2 * m)] = rfin[m];
            }
            __syncthreads();                        // block-uniform (t uniform)
            if (!kh) {                              // k-quarter 0: combine+store
                float* sbase = S + (((size_t)(cur * NL + layer)) * NPAN + w) * RDIM * 8
                                 + (size_t)(j0 + j) * 8;
                #pragma unroll
                for (int m = 0; m < 2; ++m) {
                    const int bi = bh4 + i0 + 2 * m;    // slot within panel's 8
                    float v = rfin[m];
                    #pragma unroll
                    for (int q = 1; q < NKH; ++q)
                        v += Pbuf[(((q - 1) * NPAN + w) * JW + j) * 8 + bi];
                    const float o = tanhf(v);
                    __hip_atomic_store(sbase + bi, o, __ATOMIC_RELAXED, __HIP_MEMORY_SCOPE_AGENT);
                    if (t == TT - 1)
                        Fin[(size_t)(w * 8 + bi) * HDIM + layer * RDIM + j0 + j] = o;
                }
            }
        }
        // ---- grid barrier v3: spread arrive, single summer, replicated
        //      release lines, 1-lane backoff polls (no poll storm) ----
        __syncthreads();                          // drains all waves' stores
        if (tid == 0)
            __hip_atomic_fetch_add(&cnt[(blk & 15) * CSTRIDE], 1u,
                                   __ATOMIC_RELAXED, __HIP_MEMORY_SCOPE_AGENT);
        const unsigned wrel = (unsigned)(tick + 1);
        if (blk == 0) {
            if (tid < 64) {                       // summer wave
                const unsigned wsum = wrel * (unsigned)NBLK;
                int guard = 0;
                for (;;) {
                    unsigned v = 0;
                    if (lam < 16)
                        v = __hip_atomic_load(&cnt[lam * CSTRIDE],
                                              __ATOMIC_RELAXED, __HIP_MEMORY_SCOPE_AGENT);
                    #pragma unroll
                    for (int m = 1; m <= 32; m <<= 1) v += __shfl_xor(v, m, 64);
                    if (v >= wsum) break;         // v is total on ALL lanes
                    __builtin_amdgcn_s_sleep(2);
                    if (++guard > (1 << 16)) break;   // safety valve
                }
                if (lam < 16)                     // publish release, 16 copies
                    __hip_atomic_store(&rel[lam * CSTRIDE], wrel,
                                       __ATOMIC_RELAXED, __HIP_MEMORY_SCOPE_AGENT);
            }
        } else {
            if (tid == 0) {                       // one poller lane per block
                int guard = 0;
                while (__hip_atomic_load(&rel[(blk & 15) * CSTRIDE],
                                         __ATOMIC_RELAXED, __HIP_MEMORY_SCOPE_AGENT) < wrel) {
                    __builtin_amdgcn_s_sleep(4);
                    if (++guard > (1 << 16)) break;   // safety valve
                }
            }
        }
        __syncthreads();
    }
}

// ------------------------------------------------------------- layernorm ----
__global__ void ln_kernel(const float* __restrict__ Fin,
                          const float* __restrict__ gamma,
                          const float* __restrict__ beta,
                          float* __restrict__ out)
{
    const int r = blockIdx.x, tid = threadIdx.x;
    const float* row = Fin + (size_t)r * HDIM;
    float s = 0.f, s2 = 0.f;
    for (int i = tid; i < HDIM; i += 256) { float v = row[i]; s += v; s2 += v * v; }
    for (int off = 32; off; off >>= 1) {
        s  += __shfl_down(s,  off, 64);
        s2 += __shfl_down(s2, off, 64);
    }
    __shared__ float rs[4], rs2[4];
    __shared__ float mu_s, rstd_s;
    if ((tid & 63) == 0) { rs[tid >> 6] = s; rs2[tid >> 6] = s2; }
    __syncthreads();
    if (tid == 0) {
        float S1 = rs[0] + rs[1] + rs[2] + rs[3];
        float S2 = rs2[0] + rs2[1] + rs2[2] + rs2[3];
        float mu = S1 / (float)HDIM;
        float var = S2 / (float)HDIM - mu * mu;
        mu_s = mu; rstd_s = rsqrtf(var + 1e-5f);
    }
    __syncthreads();
    float mu = mu_s, rstd = rstd_s;
    for (int i = tid; i < HDIM; i += 256)
        out[(size_t)r * HDIM + i] = (row[i] - mu) * rstd * gamma[i] + beta[i];
}

// ----------------------------------------------------------------- launch ---
extern "C" void kernel_launch(void* const* d_in, const int* in_sizes, int n_in,
                              void* d_out, int out_size, void* d_ws, size_t ws_size,
                              hipStream_t stream)
{
    const int*   x     = (const int*)d_in[0];
    const float* embed = (const float*)d_in[1];
    const float* Win0  = (const float*)d_in[2];
    const float* WinR  = (const float*)d_in[3];
    const float* Rst   = (const float*)d_in[4];
    const float* gamma = (const float*)d_in[5];
    const float* beta  = (const float*)d_in[6];
    float* out = (float*)d_out;

    char* ws = (char*)d_ws;
    unsigned* cnt = (unsigned*)ws;                    // 16 lines (arrive)
    unsigned* rel = cnt + 16 * CSTRIDE;               // 16 lines (release)
    float* S   = (float*)(ws + 8192);                                // 1MB
    float* Fin = S + S_ELEMS;                                        // 0.5MB
    float* xe  = Fin + FIN_ELEMS;                                    // 16.8MB

    hipMemsetAsync(ws, 0, 8192 + (size_t)S_ELEMS * 4, stream);       // flags+states
    gather_kernel   <<<TT,   256, 0, stream>>>(x, embed, xe);
    reservoir_kernel<<<NBLK, 1024, 0, stream>>>(Win0, WinR, Rst, xe, S, Fin, cnt, rel);
    ln_kernel       <<<BB,   256, 0, stream>>>(Fin, gamma, beta, out);
}

// Round 4
// 8007.858 us; speedup vs baseline: 1.0016x; 1.0016x over previous
//
#include <hip/hip_runtime.h>
#include <math.h>

// Deep ESN, fp32, persistent wavefront-pipelined kernel, round 11.
// R9/R10 (1024 thr, 4-way k-split) were sabotaged by the compiler's
// occupancy heuristic: it targeted 8 waves/EU -> 64 VGPRs, but the
// accumulator alone is 64 floats -> massive scratch spills (hbm_bytes
// 1.7GB -> 13.8GB). Dropping the launch-bounds hint (R10) did NOT help:
// the heuristic, not the hint, was choosing 64. R11: pin the occupancy
// target with amdgpu_waves_per_eu(4,4) -> VGPR budget 512/4 = 128, which
// R8 proved fits this inner loop spill-free. Everything else unchanged.

#define TT    512
#define RDIM  1024
#define EDIM  256
#define NL    4
#define BB    32
#define NBLK  256          // 64 blocks per layer
#define JW    16           // output columns per block
#define HDIM  (RDIM * NL)  // 4096
#define NPAN  4            // 4 panels of 8 batch rows
#define NKH   4            // k-split ways
#define CSTRIDE 32         // dwords between counter words (128B lines)

#define S_ELEMS   (2 * NL * NPAN * RDIM * 8)   // 2 parities, 1MB
#define FIN_ELEMS (BB * HDIM)

typedef float vf2 __attribute__((ext_vector_type(2)));
typedef unsigned long long ull;

__device__ __forceinline__ float2 aload2(const ull* p) {   // 8B sc1 load
    ull u = __hip_atomic_load(p, __ATOMIC_RELAXED, __HIP_MEMORY_SCOPE_AGENT);
    union { ull u; float2 f; } c; c.u = u; return c.f;
}
__device__ __forceinline__ float dpp_xor1(float x) {   // lane ^ 1
    return __int_as_float(__builtin_amdgcn_mov_dpp(__float_as_int(x), 0xB1, 0xF, 0xF, true));
}
__device__ __forceinline__ float dpp_xor2(float x) {   // lane ^ 2
    return __int_as_float(__builtin_amdgcn_mov_dpp(__float_as_int(x), 0x4E, 0xF, 0xF, true));
}

// ---------------------------------------------------------------- gather ----
// xe[t][panel][k][8b] : panel layout matching reservoir reads
__global__ void gather_kernel(const int* __restrict__ x,
                              const float* __restrict__ embed,
                              float* __restrict__ xe)
{
    __shared__ int   ids[BB];
    __shared__ float sh[BB * (EDIM + 1)];
    const int t = blockIdx.x, tid = threadIdx.x;
    if (tid < BB) ids[tid] = x[tid * TT + t];
    __syncthreads();
    for (int r = 0; r < BB; ++r)
        sh[r * (EDIM + 1) + tid] = embed[ids[r] * EDIM + tid];
    __syncthreads();
    for (int i = tid; i < NPAN * EDIM * 8; i += 256) {
        int p = i >> 11, k = (i >> 3) & (EDIM - 1), bo = i & 7;
        xe[(size_t)t * (NPAN * EDIM * 8) + i] = sh[(p * 8 + bo) * (EDIM + 1) + k];
    }
}

// ------------------------------------------------------------- reservoir ----
__global__ __launch_bounds__(1024)
__attribute__((amdgpu_waves_per_eu(4, 4)))      // pin target: 4 waves/EU -> 128 VGPR
void reservoir_kernel(
    const float* __restrict__ Win0, const float* __restrict__ WinR,
    const float* __restrict__ Rst,  const float* __restrict__ xe,
    float* __restrict__ S, float* __restrict__ Fin,
    unsigned* __restrict__ cnt, unsigned* __restrict__ rel)
{
    __shared__ float Wlds[2048 * JW];                  // 128 KB, row k = 16 floats
    __shared__ float Pbuf[(NKH - 1) * NPAN * JW * 8];  // 6 KB, cross-wave partials
    const int tid   = threadIdx.x;
    const int blk   = blockIdx.x;
    const int layer = blk >> 6;
    const int j0    = (blk & 63) * JW;
    const int Kin   = (layer == 0) ? EDIM : RDIM;

    // rows [0,1024) = R_stack col-slice, rows [1024,1024+Kin) = Win col-slice
    for (int idx = tid; idx < (RDIM + Kin) * JW; idx += 1024) {
        int k = idx >> 4, j = idx & 15;
        float wv;
        if (k < RDIM) wv = Rst[((size_t)layer * RDIM + k) * RDIM + j0 + j];
        else {
            int k2 = k - RDIM;
            wv = (layer == 0) ? Win0[(size_t)k2 * RDIM + j0 + j]
                              : WinR[((size_t)(layer - 1) * RDIM + k2) * RDIM + j0 + j];
        }
        Wlds[idx] = wv;
    }
    __syncthreads();

    const int w16 = tid >> 6;   // 16 waves
    const int w   = w16 & 3;    // panel (8 batch rows)
    const int kh  = w16 >> 2;   // k-quarter: wave reads a disjoint k-slice
    const int lam = tid & 63;
    const int kq  = lam >> 1;   // 32-way k split within wave
    const int bh  = lam & 1;    // which float4 of the 8-wide batch row
    const int bh4 = bh * 4;

    for (int tick = 0; tick < TT + NL - 1; ++tick) {
        const int t = tick - layer;
        if (t >= 0 && t < TT) {
            const int cur = tick & 1, prv = (tick - 1) & 1;
            const ull* ownp = (const ull*)(S + (((size_t)(prv * NL + layer)) * NPAN + w) * RDIM * 8);
            const ull* inps = (const ull*)(S + (((size_t)(prv * NL + layer - 1)) * NPAN + w) * RDIM * 8);
            const float4* inpx = (const float4*)(xe + ((size_t)t * NPAN + w) * (EDIM * 8));

            vf2 acc[4][8];
            #pragma unroll
            for (int i = 0; i < 4; ++i)
                #pragma unroll
                for (int jp = 0; jp < 8; ++jp) acc[i][jp] = (vf2)(0.f);

            // ---- own state @ R_stack (sc1 loads), this wave's k-quarter ----
            #pragma unroll 8
            for (int kk2 = 0; kk2 < RDIM / (32 * NKH); ++kk2) {
                const int kk = kh * (RDIM / (32 * NKH)) + kk2;
                const ull* p = ownp + (size_t)kk * 128 + lam * 2;   // 1KB/wave
                float2 v0 = aload2(p), v1 = aload2(p + 1);
                const int k = kk * 32 + kq;
                float4 wo0 = *(const float4*)&Wlds[k * JW + bh * 8];
                float4 wo1 = *(const float4*)&Wlds[k * JW + bh * 8 + 4];
                vf2 wv[8];
                wv[0] = (vf2){wo0.x, wo0.y}; wv[1] = (vf2){wo0.z, wo0.w};
                wv[2] = (vf2){wo1.x, wo1.y}; wv[3] = (vf2){wo1.z, wo1.w};
                wv[4] = (vf2){dpp_xor1(wo0.x), dpp_xor1(wo0.y)};
                wv[5] = (vf2){dpp_xor1(wo0.z), dpp_xor1(wo0.w)};
                wv[6] = (vf2){dpp_xor1(wo1.x), dpp_xor1(wo1.y)};
                wv[7] = (vf2){dpp_xor1(wo1.z), dpp_xor1(wo1.w)};
                const float vv[4] = {v0.x, v0.y, v1.x, v1.y};
                #pragma unroll
                for (int i = 0; i < 4; ++i) {
                    vf2 s = {vv[i], vv[i]};
                    #pragma unroll
                    for (int jp = 0; jp < 8; ++jp) acc[i][jp] += s * wv[jp];
                }
            }
            // ---- layer input @ Win, this wave's k-quarter ----
            #pragma unroll 8
            for (int kk2 = 0; kk2 < Kin / (32 * NKH); ++kk2) {
                const int kk = kh * (Kin / (32 * NKH)) + kk2;
                float2 v0, v1;
                if (layer == 0) {                       // xe: read-only, cached
                    float4 v = inpx[(size_t)kk * 64 + lam];
                    v0 = (float2){v.x, v.y}; v1 = (float2){v.z, v.w};
                } else {                                // state: sc1
                    const ull* p = inps + (size_t)kk * 128 + lam * 2;
                    v0 = aload2(p); v1 = aload2(p + 1);
                }
                const int k = RDIM + kk * 32 + kq;
                float4 wo0 = *(const float4*)&Wlds[k * JW + bh * 8];
                float4 wo1 = *(const float4*)&Wlds[k * JW + bh * 8 + 4];
                vf2 wv[8];
                wv[0] = (vf2){wo0.x, wo0.y}; wv[1] = (vf2){wo0.z, wo0.w};
                wv[2] = (vf2){wo1.x, wo1.y}; wv[3] = (vf2){wo1.z, wo1.w};
                wv[4] = (vf2){dpp_xor1(wo0.x), dpp_xor1(wo0.y)};
                wv[5] = (vf2){dpp_xor1(wo0.z), dpp_xor1(wo0.w)};
                wv[6] = (vf2){dpp_xor1(wo1.x), dpp_xor1(wo1.y)};
                wv[7] = (vf2){dpp_xor1(wo1.z), dpp_xor1(wo1.w)};
                const float vv[4] = {v0.x, v0.y, v1.x, v1.y};
                #pragma unroll
                for (int i = 0; i < 4; ++i) {
                    vf2 s = {vv[i], vv[i]};
                    #pragma unroll
                    for (int jp = 0; jp < 8; ++jp) acc[i][jp] += s * wv[jp];
                }
            }

            // ---- reduce-scatter over kq: 64 accs -> 2 partials per lane ----
            float r64v[64];
            #pragma unroll
            for (int i = 0; i < 4; ++i)
                #pragma unroll
                for (int jp = 0; jp < 8; ++jp) {
                    r64v[(i << 4) | (jp << 1)]     = acc[i][jp].x;
                    r64v[(i << 4) | (jp << 1) | 1] = acc[i][jp].y;
                }
            float r32v[32], r16v[16], r8v[8], r4v[4], rfin[2];
            {   const bool myb = kq & 1;                 // stage 0: DPP xor2
                #pragma unroll
                for (int m = 0; m < 32; ++m) {
                    float a = r64v[2 * m], b = r64v[2 * m + 1];
                    float send = myb ? a : b, keep = myb ? b : a;
                    r32v[m] = keep + dpp_xor2(send);
                }
            }
            {   const bool myb = (kq >> 1) & 1;          // stage 1: xor 4
                #pragma unroll
                for (int m = 0; m < 16; ++m) {
                    float a = r32v[2 * m], b = r32v[2 * m + 1];
                    float send = myb ? a : b, keep = myb ? b : a;
                    r16v[m] = keep + __shfl_xor(send, 4, 64);
                }
            }
            {   const bool myb = (kq >> 2) & 1;          // stage 2: xor 8
                #pragma unroll
                for (int m = 0; m < 8; ++m) {
                    float a = r16v[2 * m], b = r16v[2 * m + 1];
                    float send = myb ? a : b, keep = myb ? b : a;
                    r8v[m] = keep + __shfl_xor(send, 8, 64);
                }
            }
            {   const bool myb = (kq >> 3) & 1;          // stage 3: xor 16
                #pragma unroll
                for (int m = 0; m < 4; ++m) {
                    float a = r8v[2 * m], b = r8v[2 * m + 1];
                    float send = myb ? a : b, keep = myb ? b : a;
                    r4v[m] = keep + __shfl_xor(send, 16, 64);
                }
            }
            {   const bool myb = (kq >> 4) & 1;          // stage 4: xor 32
                #pragma unroll
                for (int m = 0; m < 2; ++m) {
                    float a = r4v[2 * m], b = r4v[2 * m + 1];
                    float send = myb ? a : b, keep = myb ? b : a;
                    rfin[m] = keep + __shfl_xor(send, 32, 64);
                }
            }

            // ---- cross-wave k-quarter combine via LDS, then epilogue ----
            const int i0 = kq >> 4;                 // 0..1
            const int cc = kq & 15;
            const int j  = (cc & 7) + 8 * (bh ^ (cc >> 3));   // logical col
            if (kh) {                               // k-quarters 1..3: publish
                #pragma unroll
                for (int m = 0; m < 2; ++m)
                    Pbuf[(((kh - 1) * NPAN + w) * JW + j) * 8 + (bh4 + i0 + 2 * m)] = rfin[m];
            }
            __syncthreads();                        // block-uniform (t uniform)
            if (!kh) {                              // k-quarter 0: combine+store
                float* sbase = S + (((size_t)(cur * NL + layer)) * NPAN + w) * RDIM * 8
                                 + (size_t)(j0 + j) * 8;
                #pragma unroll
                for (int m = 0; m < 2; ++m) {
                    const int bi = bh4 + i0 + 2 * m;    // slot within panel's 8
                    float v = rfin[m];
                    #pragma unroll
                    for (int q = 1; q < NKH; ++q)
                        v += Pbuf[(((q - 1) * NPAN + w) * JW + j) * 8 + bi];
                    const float o = tanhf(v);
                    __hip_atomic_store(sbase + bi, o, __ATOMIC_RELAXED, __HIP_MEMORY_SCOPE_AGENT);
                    if (t == TT - 1)
                        Fin[(size_t)(w * 8 + bi) * HDIM + layer * RDIM + j0 + j] = o;
                }
            }
        }
        // ---- grid barrier v3: spread arrive, single summer, replicated
        //      release lines, 1-lane backoff polls (no poll storm) ----
        __syncthreads();                          // drains all waves' stores
        if (tid == 0)
            __hip_atomic_fetch_add(&cnt[(blk & 15) * CSTRIDE], 1u,
                                   __ATOMIC_RELAXED, __HIP_MEMORY_SCOPE_AGENT);
        const unsigned wrel = (unsigned)(tick + 1);
        if (blk == 0) {
            if (tid < 64) {                       // summer wave
                const unsigned wsum = wrel * (unsigned)NBLK;
                int guard = 0;
                for (;;) {
                    unsigned v = 0;
                    if (lam < 16)
                        v = __hip_atomic_load(&cnt[lam * CSTRIDE],
                                              __ATOMIC_RELAXED, __HIP_MEMORY_SCOPE_AGENT);
                    #pragma unroll
                    for (int m = 1; m <= 32; m <<= 1) v += __shfl_xor(v, m, 64);
                    if (v >= wsum) break;         // v is total on ALL lanes
                    __builtin_amdgcn_s_sleep(2);
                    if (++guard > (1 << 16)) break;   // safety valve
                }
                if (lam < 16)                     // publish release, 16 copies
                    __hip_atomic_store(&rel[lam * CSTRIDE], wrel,
                                       __ATOMIC_RELAXED, __HIP_MEMORY_SCOPE_AGENT);
            }
        } else {
            if (tid == 0) {                       // one poller lane per block
                int guard = 0;
                while (__hip_atomic_load(&rel[(blk & 15) * CSTRIDE],
                                         __ATOMIC_RELAXED, __HIP_MEMORY_SCOPE_AGENT) < wrel) {
                    __builtin_amdgcn_s_sleep(4);
                    if (++guard > (1 << 16)) break;   // safety valve
                }
            }
        }
        __syncthreads();
    }
}

// ------------------------------------------------------------- layernorm ----
__global__ void ln_kernel(const float* __restrict__ Fin,
                          const float* __restrict__ gamma,
                          const float* __restrict__ beta,
                          float* __restrict__ out)
{
    const int r = blockIdx.x, tid = threadIdx.x;
    const float* row = Fin + (size_t)r * HDIM;
    float s = 0.f, s2 = 0.f;
    for (int i = tid; i < HDIM; i += 256) { float v = row[i]; s += v; s2 += v * v; }
    for (int off = 32; off; off >>= 1) {
        s  += __shfl_down(s,  off, 64);
        s2 += __shfl_down(s2, off, 64);
    }
    __shared__ float rs[4], rs2[4];
    __shared__ float mu_s, rstd_s;
    if ((tid & 63) == 0) { rs[tid >> 6] = s; rs2[tid >> 6] = s2; }
    __syncthreads();
    if (tid == 0) {
        float S1 = rs[0] + rs[1] + rs[2] + rs[3];
        float S2 = rs2[0] + rs2[1] + rs2[2] + rs2[3];
        float mu = S1 / (float)HDIM;
        float var = S2 / (float)HDIM - mu * mu;
        mu_s = mu; rstd_s = rsqrtf(var + 1e-5f);
    }
    __syncthreads();
    float mu = mu_s, rstd = rstd_s;
    for (int i = tid; i < HDIM; i += 256)
        out[(size_t)r * HDIM + i] = (row[i] - mu) * rstd * gamma[i] + beta[i];
}

// ----------------------------------------------------------------- launch ---
extern "C" void kernel_launch(void* const* d_in, const int* in_sizes, int n_in,
                              void* d_out, int out_size, void* d_ws, size_t ws_size,
                              hipStream_t stream)
{
    const int*   x     = (const int*)d_in[0];
    const float* embed = (const float*)d_in[1];
    const float* Win0  = (const float*)d_in[2];
    const float* WinR  = (const float*)d_in[3];
    const float* Rst   = (const float*)d_in[4];
    const float* gamma = (const float*)d_in[5];
    const float* beta  = (const float*)d_in[6];
    float* out = (float*)d_out;

    char* ws = (char*)d_ws;
    unsigned* cnt = (unsigned*)ws;                    // 16 lines (arrive)
    unsigned* rel = cnt + 16 * CSTRIDE;               // 16 lines (release)
    float* S   = (float*)(ws + 8192);                                // 1MB
    float* Fin = S + S_ELEMS;                                        // 0.5MB
    float* xe  = Fin + FIN_ELEMS;                                    // 16.8MB

    hipMemsetAsync(ws, 0, 8192 + (size_t)S_ELEMS * 4, stream);       // flags+states
    gather_kernel   <<<TT,   256, 0, stream>>>(x, embed, xe);
    reservoir_kernel<<<NBLK, 1024, 0, stream>>>(Win0, WinR, Rst, xe, S, Fin, cnt, rel);
    ln_kernel       <<<BB,   256, 0, stream>>>(Fin, gamma, beta, out);
}

// Round 5
// 6996.920 us; speedup vs baseline: 1.1463x; 1.1445x over previous
//
#include <hip/hip_runtime.h>
#include <math.h>

// Deep ESN, fp32, persistent wavefront-pipelined kernel, round 12.
// R9-R11: 1024-thread blocks are a dead end -- the compiler pins VGPR=64 at
// flat-WG-size 1024 regardless of launch-bounds / waves_per_eu attributes,
// spilling the 64-float accumulator (hbm 13.8GB). Reverted to the proven R8
// geometry (512 thr, 2-way k-split, VGPR=128, 6408us).
// R12 change: state LOADS switch from sc1 (MALL round-trip per access, no
// caching) to PLAIN cached float4 loads, made safe by one agent acquire
// fence (buffer_inv: invalidates L1 + non-coherent L2) per tick right after
// the grid-barrier poll. Within a tick the prev-parity state is read-only,
// so caching is legal; the per-XCD L2 then collapses the ~16x same-XCD
// fan-in of state reads to ~1 MALL fetch per line per XCD. Stores remain
// sc1-direct-to-MALL (proven visibility: pre-barrier vmcnt drain + arrive).

#define TT    512
#define RDIM  1024
#define EDIM  256
#define NL    4
#define BB    32
#define NBLK  256          // 64 blocks per layer
#define JW    16           // output columns per block
#define HDIM  (RDIM * NL)  // 4096
#define NPAN  4            // 4 panels of 8 batch rows
#define CSTRIDE 32         // dwords between counter words (128B lines)

#define S_ELEMS   (2 * NL * NPAN * RDIM * 8)   // 2 parities, 1MB
#define FIN_ELEMS (BB * HDIM)

typedef float vf2 __attribute__((ext_vector_type(2)));
typedef unsigned long long ull;

__device__ __forceinline__ float dpp_xor1(float x) {   // lane ^ 1
    return __int_as_float(__builtin_amdgcn_mov_dpp(__float_as_int(x), 0xB1, 0xF, 0xF, true));
}
__device__ __forceinline__ float dpp_xor2(float x) {   // lane ^ 2
    return __int_as_float(__builtin_amdgcn_mov_dpp(__float_as_int(x), 0x4E, 0xF, 0xF, true));
}

// ---------------------------------------------------------------- gather ----
// xe[t][panel][k][8b] : panel layout matching reservoir reads
__global__ void gather_kernel(const int* __restrict__ x,
                              const float* __restrict__ embed,
                              float* __restrict__ xe)
{
    __shared__ int   ids[BB];
    __shared__ float sh[BB * (EDIM + 1)];
    const int t = blockIdx.x, tid = threadIdx.x;
    if (tid < BB) ids[tid] = x[tid * TT + t];
    __syncthreads();
    for (int r = 0; r < BB; ++r)
        sh[r * (EDIM + 1) + tid] = embed[ids[r] * EDIM + tid];
    __syncthreads();
    for (int i = tid; i < NPAN * EDIM * 8; i += 256) {
        int p = i >> 11, k = (i >> 3) & (EDIM - 1), bo = i & 7;
        xe[(size_t)t * (NPAN * EDIM * 8) + i] = sh[(p * 8 + bo) * (EDIM + 1) + k];
    }
}

// ------------------------------------------------------------- reservoir ----
__global__ __launch_bounds__(512, 2) void reservoir_kernel(
    const float* __restrict__ Win0, const float* __restrict__ WinR,
    const float* __restrict__ Rst,  const float* __restrict__ xe,
    float* __restrict__ S, float* __restrict__ Fin,
    unsigned* __restrict__ cnt, unsigned* __restrict__ rel)
{
    __shared__ float Wlds[2048 * JW];       // 128 KB, row k = 16 floats
    __shared__ float Pbuf[NPAN * JW * 8];   // 2 KB, cross-wave k partials
    const int tid   = threadIdx.x;
    const int blk   = blockIdx.x;
    const int layer = blk >> 6;
    const int j0    = (blk & 63) * JW;
    const int Kin   = (layer == 0) ? EDIM : RDIM;

    // rows [0,1024) = R_stack col-slice, rows [1024,1024+Kin) = Win col-slice
    for (int idx = tid; idx < (RDIM + Kin) * JW; idx += 512) {
        int k = idx >> 4, j = idx & 15;
        float wv;
        if (k < RDIM) wv = Rst[((size_t)layer * RDIM + k) * RDIM + j0 + j];
        else {
            int k2 = k - RDIM;
            wv = (layer == 0) ? Win0[(size_t)k2 * RDIM + j0 + j]
                              : WinR[((size_t)(layer - 1) * RDIM + k2) * RDIM + j0 + j];
        }
        Wlds[idx] = wv;
    }
    __syncthreads();

    const int w8  = tid >> 6;   // 8 waves
    const int w   = w8 & 3;     // panel (8 batch rows)
    const int kh  = w8 >> 2;    // k-half: wave reads a disjoint k-slice
    const int lam = tid & 63;
    const int kq  = lam >> 1;   // 32-way k split within wave
    const int bh  = lam & 1;    // which float4 of the 8-wide batch row
    const int bh4 = bh * 4;

    for (int tick = 0; tick < TT + NL - 1; ++tick) {
        const int t = tick - layer;
        if (t >= 0 && t < TT) {
            const int cur = tick & 1, prv = (tick - 1) & 1;
            // Plain cached pointers (safe: per-tick acquire fence below
            // invalidates L1/L2 before any wave reaches these loads).
            const float4* ownp = (const float4*)(S + (((size_t)(prv * NL + layer)) * NPAN + w) * RDIM * 8);
            const float4* insrc = (layer == 0)
                ? (const float4*)(xe + ((size_t)t * NPAN + w) * (EDIM * 8))
                : (const float4*)(S + (((size_t)(prv * NL + layer - 1)) * NPAN + w) * RDIM * 8);

            vf2 acc[4][8];
            #pragma unroll
            for (int i = 0; i < 4; ++i)
                #pragma unroll
                for (int jp = 0; jp < 8; ++jp) acc[i][jp] = (vf2)(0.f);

            // ---- own state @ R_stack, this wave's k-half (16B plain loads) ----
            #pragma unroll 8
            for (int kk2 = 0; kk2 < RDIM / 64; ++kk2) {
                const int kk = kh * (RDIM / 64) + kk2;
                float4 v = ownp[(size_t)kk * 64 + lam];          // 1KB/wave/iter
                const int k = kk * 32 + kq;
                float4 wo0 = *(const float4*)&Wlds[k * JW + bh * 8];
                float4 wo1 = *(const float4*)&Wlds[k * JW + bh * 8 + 4];
                vf2 wv[8];
                wv[0] = (vf2){wo0.x, wo0.y}; wv[1] = (vf2){wo0.z, wo0.w};
                wv[2] = (vf2){wo1.x, wo1.y}; wv[3] = (vf2){wo1.z, wo1.w};
                wv[4] = (vf2){dpp_xor1(wo0.x), dpp_xor1(wo0.y)};
                wv[5] = (vf2){dpp_xor1(wo0.z), dpp_xor1(wo0.w)};
                wv[6] = (vf2){dpp_xor1(wo1.x), dpp_xor1(wo1.y)};
                wv[7] = (vf2){dpp_xor1(wo1.z), dpp_xor1(wo1.w)};
                const float vv[4] = {v.x, v.y, v.z, v.w};
                #pragma unroll
                for (int i = 0; i < 4; ++i) {
                    vf2 s = {vv[i], vv[i]};
                    #pragma unroll
                    for (int jp = 0; jp < 8; ++jp) acc[i][jp] += s * wv[jp];
                }
            }
            // ---- layer input @ Win, this wave's k-half (16B plain loads) ----
            #pragma unroll 8
            for (int kk2 = 0; kk2 < Kin / 64; ++kk2) {
                const int kk = kh * (Kin / 64) + kk2;
                float4 v = insrc[(size_t)kk * 64 + lam];
                const int k = RDIM + kk * 32 + kq;
                float4 wo0 = *(const float4*)&Wlds[k * JW + bh * 8];
                float4 wo1 = *(const float4*)&Wlds[k * JW + bh * 8 + 4];
                vf2 wv[8];
                wv[0] = (vf2){wo0.x, wo0.y}; wv[1] = (vf2){wo0.z, wo0.w};
                wv[2] = (vf2){wo1.x, wo1.y}; wv[3] = (vf2){wo1.z, wo1.w};
                wv[4] = (vf2){dpp_xor1(wo0.x), dpp_xor1(wo0.y)};
                wv[5] = (vf2){dpp_xor1(wo0.z), dpp_xor1(wo0.w)};
                wv[6] = (vf2){dpp_xor1(wo1.x), dpp_xor1(wo1.y)};
                wv[7] = (vf2){dpp_xor1(wo1.z), dpp_xor1(wo1.w)};
                const float vv[4] = {v.x, v.y, v.z, v.w};
                #pragma unroll
                for (int i = 0; i < 4; ++i) {
                    vf2 s = {vv[i], vv[i]};
                    #pragma unroll
                    for (int jp = 0; jp < 8; ++jp) acc[i][jp] += s * wv[jp];
                }
            }

            // ---- reduce-scatter over kq: 64 accs -> 2 partials per lane ----
            float r64v[64];
            #pragma unroll
            for (int i = 0; i < 4; ++i)
                #pragma unroll
                for (int jp = 0; jp < 8; ++jp) {
                    r64v[(i << 4) | (jp << 1)]     = acc[i][jp].x;
                    r64v[(i << 4) | (jp << 1) | 1] = acc[i][jp].y;
                }
            float r32v[32], r16v[16], r8v[8], r4v[4], rfin[2];
            {   const bool myb = kq & 1;                 // stage 0: DPP xor2
                #pragma unroll
                for (int m = 0; m < 32; ++m) {
                    float a = r64v[2 * m], b = r64v[2 * m + 1];
                    float send = myb ? a : b, keep = myb ? b : a;
                    r32v[m] = keep + dpp_xor2(send);
                }
            }
            {   const bool myb = (kq >> 1) & 1;          // stage 1: xor 4
                #pragma unroll
                for (int m = 0; m < 16; ++m) {
                    float a = r32v[2 * m], b = r32v[2 * m + 1];
                    float send = myb ? a : b, keep = myb ? b : a;
                    r16v[m] = keep + __shfl_xor(send, 4, 64);
                }
            }
            {   const bool myb = (kq >> 2) & 1;          // stage 2: xor 8
                #pragma unroll
                for (int m = 0; m < 8; ++m) {
                    float a = r16v[2 * m], b = r16v[2 * m + 1];
                    float send = myb ? a : b, keep = myb ? b : a;
                    r8v[m] = keep + __shfl_xor(send, 8, 64);
                }
            }
            {   const bool myb = (kq >> 3) & 1;          // stage 3: xor 16
                #pragma unroll
                for (int m = 0; m < 4; ++m) {
                    float a = r8v[2 * m], b = r8v[2 * m + 1];
                    float send = myb ? a : b, keep = myb ? b : a;
                    r4v[m] = keep + __shfl_xor(send, 16, 64);
                }
            }
            {   const bool myb = (kq >> 4) & 1;          // stage 4: xor 32
                #pragma unroll
                for (int m = 0; m < 2; ++m) {
                    float a = r4v[2 * m], b = r4v[2 * m + 1];
                    float send = myb ? a : b, keep = myb ? b : a;
                    rfin[m] = keep + __shfl_xor(send, 32, 64);
                }
            }

            // ---- cross-wave k-half combine via LDS, then epilogue ----
            const int i0 = kq >> 4;                 // 0..1
            const int cc = kq & 15;
            const int j  = (cc & 7) + 8 * (bh ^ (cc >> 3));   // logical col
            if (kh) {                               // k-half 1: publish partial
                #pragma unroll
                for (int m = 0; m < 2; ++m)
                    Pbuf[(w * JW + j) * 8 + (bh4 + i0 + 2 * m)] = rfin[m];
            }
            __syncthreads();                        // block-uniform (t uniform)
            if (!kh) {                              // k-half 0: combine + store
                float* sbase = S + (((size_t)(cur * NL + layer)) * NPAN + w) * RDIM * 8
                                 + (size_t)(j0 + j) * 8;
                #pragma unroll
                for (int m = 0; m < 2; ++m) {
                    const int bi = bh4 + i0 + 2 * m;    // slot within panel's 8
                    const float o = tanhf(rfin[m] + Pbuf[(w * JW + j) * 8 + bi]);
                    // sc1 store: direct to MALL, drained by the pre-barrier
                    // vmcnt(0) -> visible to all XCDs before arrive.
                    __hip_atomic_store(sbase + bi, o, __ATOMIC_RELAXED, __HIP_MEMORY_SCOPE_AGENT);
                    if (t == TT - 1)
                        Fin[(size_t)(w * 8 + bi) * HDIM + layer * RDIM + j0 + j] = o;
                }
            }
        }
        // ---- grid barrier v3 + per-tick acquire fence for plain loads ----
        __syncthreads();                          // drains all waves' stores
        if (tid == 0)
            __hip_atomic_fetch_add(&cnt[(blk & 15) * CSTRIDE], 1u,
                                   __ATOMIC_RELAXED, __HIP_MEMORY_SCOPE_AGENT);
        const unsigned wrel = (unsigned)(tick + 1);
        if (blk == 0) {
            if (tid < 64) {                       // summer wave
                const unsigned wsum = wrel * (unsigned)NBLK;
                int guard = 0;
                for (;;) {
                    unsigned v = 0;
                    if (lam < 16)
                        v = __hip_atomic_load(&cnt[lam * CSTRIDE],
                                              __ATOMIC_RELAXED, __HIP_MEMORY_SCOPE_AGENT);
                    #pragma unroll
                    for (int m = 1; m <= 32; m <<= 1) v += __shfl_xor(v, m, 64);
                    if (v >= wsum) break;         // v is total on ALL lanes
                    __builtin_amdgcn_s_sleep(2);
                    if (++guard > (1 << 16)) break;   // safety valve
                }
                if (lam < 16)                     // publish release, 16 copies
                    __hip_atomic_store(&rel[lam * CSTRIDE], wrel,
                                       __ATOMIC_RELAXED, __HIP_MEMORY_SCOPE_AGENT);
                // invalidate L1 + non-coherent L2 before next tick's plain loads
                __builtin_amdgcn_fence(__ATOMIC_ACQUIRE, "agent");
            }
        } else {
            if (tid == 0) {                       // one poller lane per block
                int guard = 0;
                while (__hip_atomic_load(&rel[(blk & 15) * CSTRIDE],
                                         __ATOMIC_RELAXED, __HIP_MEMORY_SCOPE_AGENT) < wrel) {
                    __builtin_amdgcn_s_sleep(4);
                    if (++guard > (1 << 16)) break;   // safety valve
                }
                // invalidate L1 + non-coherent L2 before next tick's plain loads
                __builtin_amdgcn_fence(__ATOMIC_ACQUIRE, "agent");
            }
        }
        __syncthreads();                          // orders the inv before all waves' loads
    }
}

// ------------------------------------------------------------- layernorm ----
__global__ void ln_kernel(const float* __restrict__ Fin,
                          const float* __restrict__ gamma,
                          const float* __restrict__ beta,
                          float* __restrict__ out)
{
    const int r = blockIdx.x, tid = threadIdx.x;
    const float* row = Fin + (size_t)r * HDIM;
    float s = 0.f, s2 = 0.f;
    for (int i = tid; i < HDIM; i += 256) { float v = row[i]; s += v; s2 += v * v; }
    for (int off = 32; off; off >>= 1) {
        s  += __shfl_down(s,  off, 64);
        s2 += __shfl_down(s2, off, 64);
    }
    __shared__ float rs[4], rs2[4];
    __shared__ float mu_s, rstd_s;
    if ((tid & 63) == 0) { rs[tid >> 6] = s; rs2[tid >> 6] = s2; }
    __syncthreads();
    if (tid == 0) {
        float S1 = rs[0] + rs[1] + rs[2] + rs[3];
        float S2 = rs2[0] + rs2[1] + rs2[2] + rs2[3];
        float mu = S1 / (float)HDIM;
        float var = S2 / (float)HDIM - mu * mu;
        mu_s = mu; rstd_s = rsqrtf(var + 1e-5f);
    }
    __syncthreads();
    float mu = mu_s, rstd = rstd_s;
    for (int i = tid; i < HDIM; i += 256)
        out[(size_t)r * HDIM + i] = (row[i] - mu) * rstd * gamma[i] + beta[i];
}

// ----------------------------------------------------------------- launch ---
extern "C" void kernel_launch(void* const* d_in, const int* in_sizes, int n_in,
                              void* d_out, int out_size, void* d_ws, size_t ws_size,
                              hipStream_t stream)
{
    const int*   x     = (const int*)d_in[0];
    const float* embed = (const float*)d_in[1];
    const float* Win0  = (const float*)d_in[2];
    const float* WinR  = (const float*)d_in[3];
    const float* Rst   = (const float*)d_in[4];
    const float* gamma = (const float*)d_in[5];
    const float* beta  = (const float*)d_in[6];
    float* out = (float*)d_out;

    char* ws = (char*)d_ws;
    unsigned* cnt = (unsigned*)ws;                    // 16 lines (arrive)
    unsigned* rel = cnt + 16 * CSTRIDE;               // 16 lines (release)
    float* S   = (float*)(ws + 8192);                                // 1MB
    float* Fin = S + S_ELEMS;                                        // 0.5MB
    float* xe  = Fin + FIN_ELEMS;                                    // 16.8MB

    hipMemsetAsync(ws, 0, 8192 + (size_t)S_ELEMS * 4, stream);       // flags+states
    gather_kernel   <<<TT,   256, 0, stream>>>(x, embed, xe);
    reservoir_kernel<<<NBLK, 512, 0, stream>>>(Win0, WinR, Rst, xe, S, Fin, cnt, rel);
    ln_kernel       <<<BB,   256, 0, stream>>>(Fin, gamma, beta, out);
}

// Round 6
// 4839.875 us; speedup vs baseline: 1.6572x; 1.4457x over previous
//
#include <hip/hip_runtime.h>
#include <math.h>

// Deep ESN, fp32, persistent wavefront-pipelined kernel, round 13.
// R12 (plain cached loads + per-tick agent acquire fence) REGRESSED
// (6408->6997): 32 unsynchronized buffer_inv per XCD per tick thrash the L2
// mid-tick, so the fan-in collapse never happens. Conclusion: coherent state
// reads must go to MALL; optimize THAT path instead.
// R13 = R8 geometry/semantics (512 thr, 2-way k-split, sc1 stores, same
// barrier) with the coherent loads rebuilt:
//   - 16B global_load_dwordx4 sc0 sc1 (inline asm): halves request count
//     (7.6M -> 3.8M per tick), same bytes.
//   - explicit depth-8 pipeline with counted s_waitcnt vmcnt(N), the wait
//     tied to its buffer via "+v" in-out (data-dep; no hoist hazard).
//   - tick body templated on <KIN, SCIN> so all indices are compile-time
//     (no runtime-indexed register arrays -> no scratch).

#define TT    512
#define RDIM  1024
#define EDIM  256
#define NL    4
#define BB    32
#define NBLK  256          // 64 blocks per layer
#define JW    16           // output columns per block
#define HDIM  (RDIM * NL)  // 4096
#define NPAN  4            // 4 panels of 8 batch rows
#define CSTRIDE 32         // dwords between counter words (128B lines)

#define S_ELEMS   (2 * NL * NPAN * RDIM * 8)   // 2 parities, 1MB
#define FIN_ELEMS (BB * HDIM)

typedef float vf2 __attribute__((ext_vector_type(2)));
typedef float vf4 __attribute__((ext_vector_type(4)));

__device__ __forceinline__ float dpp_xor1(float x) {   // lane ^ 1
    return __int_as_float(__builtin_amdgcn_mov_dpp(__float_as_int(x), 0xB1, 0xF, 0xF, true));
}
__device__ __forceinline__ float dpp_xor2(float x) {   // lane ^ 2
    return __int_as_float(__builtin_amdgcn_mov_dpp(__float_as_int(x), 0x4E, 0xF, 0xF, true));
}

// 16B coherent load (bypass L1+L2 -> MALL), issue only, no wait.
__device__ __forceinline__ void gload_sc(vf4& d, const void* p) {
    asm volatile("global_load_dwordx4 %0, %1, off sc0 sc1" : "=v"(d) : "v"(p));
}
// 16B plain cached load (xe: read-only input, L2-cacheable), issue only.
__device__ __forceinline__ void gload_pl(vf4& d, const void* p) {
    asm volatile("global_load_dwordx4 %0, %1, off" : "=v"(d) : "v"(p));
}
// Counted wait, data-tied to the buffer being consumed.
__device__ __forceinline__ void vwait(int wn, vf4& r) {
    if (wn >= 7)      asm volatile("s_waitcnt vmcnt(7)" : "+v"(r));
    else if (wn == 6) asm volatile("s_waitcnt vmcnt(6)" : "+v"(r));
    else if (wn == 5) asm volatile("s_waitcnt vmcnt(5)" : "+v"(r));
    else if (wn == 4) asm volatile("s_waitcnt vmcnt(4)" : "+v"(r));
    else if (wn == 3) asm volatile("s_waitcnt vmcnt(3)" : "+v"(r));
    else if (wn == 2) asm volatile("s_waitcnt vmcnt(2)" : "+v"(r));
    else if (wn == 1) asm volatile("s_waitcnt vmcnt(1)" : "+v"(r));
    else              asm volatile("s_waitcnt vmcnt(0)" : "+v"(r));
}

// ---------------------------------------------------------------- gather ----
// xe[t][panel][k][8b] : panel layout matching reservoir reads
__global__ void gather_kernel(const int* __restrict__ x,
                              const float* __restrict__ embed,
                              float* __restrict__ xe)
{
    __shared__ int   ids[BB];
    __shared__ float sh[BB * (EDIM + 1)];
    const int t = blockIdx.x, tid = threadIdx.x;
    if (tid < BB) ids[tid] = x[tid * TT + t];
    __syncthreads();
    for (int r = 0; r < BB; ++r)
        sh[r * (EDIM + 1) + tid] = embed[ids[r] * EDIM + tid];
    __syncthreads();
    for (int i = tid; i < NPAN * EDIM * 8; i += 256) {
        int p = i >> 11, k = (i >> 3) & (EDIM - 1), bo = i & 7;
        xe[(size_t)t * (NPAN * EDIM * 8) + i] = sh[(p * 8 + bo) * (EDIM + 1) + k];
    }
}

// ------------------------------------------------- per-tick compute body ----
// Depth-8 pipelined MALL loads + pk-fma consume. All indices compile-time.
template<int KIN, bool SCIN>
__device__ __forceinline__ void tick_body(
    const float* __restrict__ Sown, const float* __restrict__ Sin,
    const float* __restrict__ Wlds,
    const int kh, const int lam, const int kq, const int bh,
    vf2 acc[4][8])
{
    constexpr int NOWN = RDIM / 64;     // 16 iters of 16B per lane
    constexpr int NIN  = KIN / 64;      // 16 (state) or 4 (xe)
    constexpr int NT   = NOWN + NIN;

    const vf4* ownp = (const vf4*)Sown;
    const vf4* inp  = (const vf4*)Sin;

    vf4 b[8];

    // prologue: fill the 8-deep queue (first 8 loads are all own-segment)
    #pragma unroll
    for (int i = 0; i < 8; ++i)
        gload_sc(b[i], (const void*)(ownp + (size_t)(kh * NOWN + i) * 64 + lam));

    #pragma unroll
    for (int i = 0; i < NT; ++i) {
        vf4& br = b[i & 7];
        const int wn = (NT - 1 - i) < 7 ? (NT - 1 - i) : 7;
        vwait(wn, br);
        const vf4 v = br;
        if (i + 8 < NT) {
            const int n = i + 8;
            if (n < NOWN) {
                gload_sc(br, (const void*)(ownp + (size_t)(kh * NOWN + n) * 64 + lam));
            } else {
                const void* p = (const void*)(inp + (size_t)(kh * NIN + (n - NOWN)) * 64 + lam);
                if (SCIN) gload_sc(br, p);
                else      gload_pl(br, p);
            }
        }
        const int k = (i < NOWN) ? ((kh * NOWN + i) * 32 + kq)
                                 : (RDIM + (kh * NIN + (i - NOWN)) * 32 + kq);
        const float* wr = &Wlds[k * JW + bh * 8];
        float4 wo0 = *(const float4*)wr;
        float4 wo1 = *(const float4*)(wr + 4);
        vf2 wv[8];
        wv[0] = (vf2){wo0.x, wo0.y}; wv[1] = (vf2){wo0.z, wo0.w};
        wv[2] = (vf2){wo1.x, wo1.y}; wv[3] = (vf2){wo1.z, wo1.w};
        wv[4] = (vf2){dpp_xor1(wo0.x), dpp_xor1(wo0.y)};
        wv[5] = (vf2){dpp_xor1(wo0.z), dpp_xor1(wo0.w)};
        wv[6] = (vf2){dpp_xor1(wo1.x), dpp_xor1(wo1.y)};
        wv[7] = (vf2){dpp_xor1(wo1.z), dpp_xor1(wo1.w)};
        const float vv[4] = {v[0], v[1], v[2], v[3]};
        #pragma unroll
        for (int q = 0; q < 4; ++q) {
            vf2 s = {vv[q], vv[q]};
            #pragma unroll
            for (int jp = 0; jp < 8; ++jp) acc[q][jp] += s * wv[jp];
        }
    }
}

// ------------------------------------------------------------- reservoir ----
__global__ __launch_bounds__(512, 2) void reservoir_kernel(
    const float* __restrict__ Win0, const float* __restrict__ WinR,
    const float* __restrict__ Rst,  const float* __restrict__ xe,
    float* __restrict__ S, float* __restrict__ Fin,
    unsigned* __restrict__ cnt, unsigned* __restrict__ rel)
{
    __shared__ float Wlds[2048 * JW];       // 128 KB, row k = 16 floats
    __shared__ float Pbuf[NPAN * JW * 8];   // 2 KB, cross-wave k partials
    const int tid   = threadIdx.x;
    const int blk   = blockIdx.x;
    const int layer = blk >> 6;
    const int j0    = (blk & 63) * JW;
    const int Kin   = (layer == 0) ? EDIM : RDIM;

    // rows [0,1024) = R_stack col-slice, rows [1024,1024+Kin) = Win col-slice
    for (int idx = tid; idx < (RDIM + Kin) * JW; idx += 512) {
        int k = idx >> 4, j = idx & 15;
        float wv;
        if (k < RDIM) wv = Rst[((size_t)layer * RDIM + k) * RDIM + j0 + j];
        else {
            int k2 = k - RDIM;
            wv = (layer == 0) ? Win0[(size_t)k2 * RDIM + j0 + j]
                              : WinR[((size_t)(layer - 1) * RDIM + k2) * RDIM + j0 + j];
        }
        Wlds[idx] = wv;
    }
    __syncthreads();

    const int w8  = tid >> 6;   // 8 waves
    const int w   = w8 & 3;     // panel (8 batch rows)
    const int kh  = w8 >> 2;    // k-half: wave reads a disjoint k-slice
    const int lam = tid & 63;
    const int kq  = lam >> 1;   // 32-way k split within wave
    const int bh  = lam & 1;    // which float4 of the 8-wide batch row
    const int bh4 = bh * 4;

    for (int tick = 0; tick < TT + NL - 1; ++tick) {
        const int t = tick - layer;
        if (t >= 0 && t < TT) {
            const int cur = tick & 1, prv = (tick - 1) & 1;
            const float* Sown = S + (((size_t)(prv * NL + layer)) * NPAN + w) * RDIM * 8;
            const float* Sin  = (layer == 0)
                ? (xe + ((size_t)t * NPAN + w) * (EDIM * 8))
                : (S + (((size_t)(prv * NL + layer - 1)) * NPAN + w) * RDIM * 8);

            vf2 acc[4][8];
            #pragma unroll
            for (int i = 0; i < 4; ++i)
                #pragma unroll
                for (int jp = 0; jp < 8; ++jp) acc[i][jp] = (vf2)(0.f);

            if (layer == 0) tick_body<EDIM, false>(Sown, Sin, Wlds, kh, lam, kq, bh, acc);
            else            tick_body<RDIM, true >(Sown, Sin, Wlds, kh, lam, kq, bh, acc);

            // ---- reduce-scatter over kq: 64 accs -> 2 partials per lane ----
            float r64v[64];
            #pragma unroll
            for (int i = 0; i < 4; ++i)
                #pragma unroll
                for (int jp = 0; jp < 8; ++jp) {
                    r64v[(i << 4) | (jp << 1)]     = acc[i][jp].x;
                    r64v[(i << 4) | (jp << 1) | 1] = acc[i][jp].y;
                }
            float r32v[32], r16v[16], r8v[8], r4v[4], rfin[2];
            {   const bool myb = kq & 1;                 // stage 0: DPP xor2
                #pragma unroll
                for (int m = 0; m < 32; ++m) {
                    float a = r64v[2 * m], b = r64v[2 * m + 1];
                    float send = myb ? a : b, keep = myb ? b : a;
                    r32v[m] = keep + dpp_xor2(send);
                }
            }
            {   const bool myb = (kq >> 1) & 1;          // stage 1: xor 4
                #pragma unroll
                for (int m = 0; m < 16; ++m) {
                    float a = r32v[2 * m], b = r32v[2 * m + 1];
                    float send = myb ? a : b, keep = myb ? b : a;
                    r16v[m] = keep + __shfl_xor(send, 4, 64);
                }
            }
            {   const bool myb = (kq >> 2) & 1;          // stage 2: xor 8
                #pragma unroll
                for (int m = 0; m < 8; ++m) {
                    float a = r16v[2 * m], b = r16v[2 * m + 1];
                    float send = myb ? a : b, keep = myb ? b : a;
                    r8v[m] = keep + __shfl_xor(send, 8, 64);
                }
            }
            {   const bool myb = (kq >> 3) & 1;          // stage 3: xor 16
                #pragma unroll
                for (int m = 0; m < 4; ++m) {
                    float a = r8v[2 * m], b = r8v[2 * m + 1];
                    float send = myb ? a : b, keep = myb ? b : a;
                    r4v[m] = keep + __shfl_xor(send, 16, 64);
                }
            }
            {   const bool myb = (kq >> 4) & 1;          // stage 4: xor 32
                #pragma unroll
                for (int m = 0; m < 2; ++m) {
                    float a = r4v[2 * m], b = r4v[2 * m + 1];
                    float send = myb ? a : b, keep = myb ? b : a;
                    rfin[m] = keep + __shfl_xor(send, 32, 64);
                }
            }

            // ---- cross-wave k-half combine via LDS, then epilogue ----
            const int i0 = kq >> 4;                 // 0..1
            const int cc = kq & 15;
            const int j  = (cc & 7) + 8 * (bh ^ (cc >> 3));   // logical col
            if (kh) {                               // k-half 1: publish partial
                #pragma unroll
                for (int m = 0; m < 2; ++m)
                    Pbuf[(w * JW + j) * 8 + (bh4 + i0 + 2 * m)] = rfin[m];
            }
            __syncthreads();                        // block-uniform (t uniform)
            if (!kh) {                              // k-half 0: combine + store
                float* sbase = S + (((size_t)(cur * NL + layer)) * NPAN + w) * RDIM * 8
                                 + (size_t)(j0 + j) * 8;
                #pragma unroll
                for (int m = 0; m < 2; ++m) {
                    const int bi = bh4 + i0 + 2 * m;    // slot within panel's 8
                    const float o = tanhf(rfin[m] + Pbuf[(w * JW + j) * 8 + bi]);
                    // sc1 store: direct to MALL, drained by pre-barrier vmcnt(0)
                    __hip_atomic_store(sbase + bi, o, __ATOMIC_RELAXED, __HIP_MEMORY_SCOPE_AGENT);
                    if (t == TT - 1)
                        Fin[(size_t)(w * 8 + bi) * HDIM + layer * RDIM + j0 + j] = o;
                }
            }
        }
        // ---- grid barrier v3: spread arrive, single summer, replicated
        //      release lines, 1-lane backoff polls (no poll storm) ----
        __syncthreads();                          // drains all waves' stores
        if (tid == 0)
            __hip_atomic_fetch_add(&cnt[(blk & 15) * CSTRIDE], 1u,
                                   __ATOMIC_RELAXED, __HIP_MEMORY_SCOPE_AGENT);
        const unsigned wrel = (unsigned)(tick + 1);
        if (blk == 0) {
            if (tid < 64) {                       // summer wave
                const unsigned wsum = wrel * (unsigned)NBLK;
                int guard = 0;
                for (;;) {
                    unsigned v = 0;
                    if (lam < 16)
                        v = __hip_atomic_load(&cnt[lam * CSTRIDE],
                                              __ATOMIC_RELAXED, __HIP_MEMORY_SCOPE_AGENT);
                    #pragma unroll
                    for (int m = 1; m <= 32; m <<= 1) v += __shfl_xor(v, m, 64);
                    if (v >= wsum) break;         // v is total on ALL lanes
                    __builtin_amdgcn_s_sleep(2);
                    if (++guard > (1 << 16)) break;   // safety valve
                }
                if (lam < 16)                     // publish release, 16 copies
                    __hip_atomic_store(&rel[lam * CSTRIDE], wrel,
                                       __ATOMIC_RELAXED, __HIP_MEMORY_SCOPE_AGENT);
            }
        } else {
            if (tid == 0) {                       // one poller lane per block
                int guard = 0;
                while (__hip_atomic_load(&rel[(blk & 15) * CSTRIDE],
                                         __ATOMIC_RELAXED, __HIP_MEMORY_SCOPE_AGENT) < wrel) {
                    __builtin_amdgcn_s_sleep(4);
                    if (++guard > (1 << 16)) break;   // safety valve
                }
            }
        }
        __syncthreads();
    }
}

// ------------------------------------------------------------- layernorm ----
__global__ void ln_kernel(const float* __restrict__ Fin,
                          const float* __restrict__ gamma,
                          const float* __restrict__ beta,
                          float* __restrict__ out)
{
    const int r = blockIdx.x, tid = threadIdx.x;
    const float* row = Fin + (size_t)r * HDIM;
    float s = 0.f, s2 = 0.f;
    for (int i = tid; i < HDIM; i += 256) { float v = row[i]; s += v; s2 += v * v; }
    for (int off = 32; off; off >>= 1) {
        s  += __shfl_down(s,  off, 64);
        s2 += __shfl_down(s2, off, 64);
    }
    __shared__ float rs[4], rs2[4];
    __shared__ float mu_s, rstd_s;
    if ((tid & 63) == 0) { rs[tid >> 6] = s; rs2[tid >> 6] = s2; }
    __syncthreads();
    if (tid == 0) {
        float S1 = rs[0] + rs[1] + rs[2] + rs[3];
        float S2 = rs2[0] + rs2[1] + rs2[2] + rs2[3];
        float mu = S1 / (float)HDIM;
        float var = S2 / (float)HDIM - mu * mu;
        mu_s = mu; rstd_s = rsqrtf(var + 1e-5f);
    }
    __syncthreads();
    float mu = mu_s, rstd = rstd_s;
    for (int i = tid; i < HDIM; i += 256)
        out[(size_t)r * HDIM + i] = (row[i] - mu) * rstd * gamma[i] + beta[i];
}

// ----------------------------------------------------------------- launch ---
extern "C" void kernel_launch(void* const* d_in, const int* in_sizes, int n_in,
                              void* d_out, int out_size, void* d_ws, size_t ws_size,
                              hipStream_t stream)
{
    const int*   x     = (const int*)d_in[0];
    const float* embed = (const float*)d_in[1];
    const float* Win0  = (const float*)d_in[2];
    const float* WinR  = (const float*)d_in[3];
    const float* Rst   = (const float*)d_in[4];
    const float* gamma = (const float*)d_in[5];
    const float* beta  = (const float*)d_in[6];
    float* out = (float*)d_out;

    char* ws = (char*)d_ws;
    unsigned* cnt = (unsigned*)ws;                    // 16 lines (arrive)
    unsigned* rel = cnt + 16 * CSTRIDE;               // 16 lines (release)
    float* S   = (float*)(ws + 8192);                                // 1MB
    float* Fin = S + S_ELEMS;                                        // 0.5MB
    float* xe  = Fin + FIN_ELEMS;                                    // 16.8MB

    hipMemsetAsync(ws, 0, 8192 + (size_t)S_ELEMS * 4, stream);       // flags+states
    gather_kernel   <<<TT,   256, 0, stream>>>(x, embed, xe);
    reservoir_kernel<<<NBLK, 512, 0, stream>>>(Win0, WinR, Rst, xe, S, Fin, cnt, rel);
    ln_kernel       <<<BB,   256, 0, stream>>>(Fin, gamma, beta, out);
}